// Round 2
// baseline (942.270 us; speedup 1.0000x reference)
//
#include <hip/hip_runtime.h>
#include <hip/hip_bf16.h>

#define E_ 8
#define K_ 2
#define D_ 1024
#define F_ 4096
#define FS_ 2048
#define N_ 2048
#define ROWS_CAP 4352
#define NCHUNK 8
#define CHUNK_CAP 8

typedef __bf16 bf16x8 __attribute__((ext_vector_type(8)));
typedef float f32x4 __attribute__((ext_vector_type(4)));

static __device__ __forceinline__ unsigned short f2bf(float f) {
  union { float f; unsigned int u; } v; v.f = f;
  unsigned int u = v.u;
  return (unsigned short)((u + 0x7FFF + ((u >> 16) & 1)) >> 16);  // RNE
}

// async global->LDS, 16B per lane; LDS dest = wave-uniform base + lane*16
static __device__ __forceinline__ void gload16(const unsigned short* gp, unsigned short* lp) {
  __builtin_amdgcn_global_load_lds(
      (const __attribute__((address_space(1))) unsigned int*)gp,
      (__attribute__((address_space(3))) unsigned int*)lp, 16, 0, 0);
}

__global__ void init_k(int* counts) {
  if (threadIdx.x < E_) counts[threadIdx.x] = 0;
}

// One wave per token: logits, softmax, top-2, counts; casts x row to bf16.
__global__ void router_k(const float* __restrict__ x, const float* __restrict__ gw,
                         unsigned short* __restrict__ xbf, float* __restrict__ topw,
                         int* __restrict__ topi, int* __restrict__ counts) {
  int wave = threadIdx.x >> 6, lane = threadIdx.x & 63;
  int n = blockIdx.x * 4 + wave;
  const float* xr = x + (size_t)n * D_;
  float v[16];
#pragma unroll
  for (int j = 0; j < 16; ++j) v[j] = xr[lane + 64 * j];
#pragma unroll
  for (int j = 0; j < 16; ++j) xbf[(size_t)n * D_ + lane + 64 * j] = f2bf(v[j]);
  float logit[E_];
  for (int e = 0; e < E_; ++e) {
    const float* g = gw + e * D_;
    float acc = 0.f;
#pragma unroll
    for (int j = 0; j < 16; ++j) acc += v[j] * g[lane + 64 * j];
#pragma unroll
    for (int off = 32; off > 0; off >>= 1) acc += __shfl_down(acc, off, 64);
    logit[e] = __shfl(acc, 0, 64);
  }
  if (lane == 0) {
    float m = logit[0];
    for (int e = 1; e < E_; ++e) m = fmaxf(m, logit[e]);
    float p[E_], s = 0.f;
    for (int e = 0; e < E_; ++e) { p[e] = expf(logit[e] - m); s += p[e]; }
    float inv = 1.f / s;
    for (int e = 0; e < E_; ++e) p[e] *= inv;
    int i0 = 0;
    for (int e = 1; e < E_; ++e) if (p[e] > p[i0]) i0 = e;
    int i1 = (i0 == 0) ? 1 : 0;
    for (int e = 0; e < E_; ++e) if (e != i0 && p[e] > p[i1]) i1 = e;
    topi[n * 2] = i0; topi[n * 2 + 1] = i1;
    topw[n * 2] = p[i0]; topw[n * 2 + 1] = p[i1];
    atomicAdd(&counts[i0], 1);
    atomicAdd(&counts[i1], 1);
  }
}

// prefix sum + XCD-chunked (expert, mtile) table: each expert's tiles are
// binned into one of 8 chunks (least-loaded greedy) so all M-tiles that share
// a weight panel run on the SAME XCD (gridDim.x==8 -> flat%8 == chunk).
__global__ void scan_k(const int* __restrict__ counts, int* __restrict__ offs,
                       int* __restrict__ cursor, int* __restrict__ tile_e,
                       int* __restrict__ tile_m) {
  if (threadIdx.x == 0) {
    int load[NCHUNK];
    for (int c = 0; c < NCHUNK; ++c) load[c] = 0;
    for (int i = 0; i < NCHUNK * CHUNK_CAP; ++i) tile_e[i] = -1;
    int o = 0;
    for (int e = 0; e < E_; ++e) {
      offs[e] = o;
      int c = counts[e];
      int mt = (c + 127) >> 7;
      int best = 0;
      for (int c2 = 1; c2 < NCHUNK; ++c2) if (load[c2] < load[best]) best = c2;
      for (int m = 0; m < mt; ++m) {
        int ch = best;
        if (load[ch] >= CHUNK_CAP) {
          ch = 0;
          for (int c2 = 1; c2 < NCHUNK; ++c2) if (load[c2] < load[ch]) ch = c2;
        }
        tile_e[ch * CHUNK_CAP + load[ch]] = e;
        tile_m[ch * CHUNK_CAP + load[ch]] = m;
        load[ch]++;
      }
      o += c; cursor[e] = 0;
    }
    offs[E_] = o;
  }
}

__global__ void fill_k(const int* __restrict__ topi, const float* __restrict__ topw,
                       const int* __restrict__ offs,
                       int* __restrict__ cursor, int* __restrict__ rowlist,
                       int* __restrict__ slot_of, float* __restrict__ roww) {
  int n = blockIdx.x * blockDim.x + threadIdx.x;
  if (n >= N_) return;
  for (int k = 0; k < K_; ++k) {
    int e = topi[n * 2 + k];
    int pos = offs[e] + atomicAdd(&cursor[e], 1);
    rowlist[pos] = n;
    slot_of[n * 2 + k] = pos;
    roww[pos] = topw[n * 2 + k];
  }
}

// fp32 [R,C] -> bf16 [C,R] (per batch z). float4 loads, coalesced both sides.
__global__ void transpose_cvt_k(const float* __restrict__ in, unsigned short* __restrict__ out,
                                int R, int C) {
  __shared__ float tile[64][65];
  int cb = blockIdx.x * 64, rb = blockIdx.y * 64;
  const float* ip = in + (size_t)blockIdx.z * R * C;
  unsigned short* op = out + (size_t)blockIdx.z * R * C;
  int t = threadIdx.x;
  int cg = (t & 15) * 4, r0 = t >> 4;
#pragma unroll
  for (int p = 0; p < 4; ++p) {
    int r = r0 + p * 16;
    float4 v = *(const float4*)&ip[(size_t)(rb + r) * C + cb + cg];
    tile[r][cg] = v.x; tile[r][cg + 1] = v.y; tile[r][cg + 2] = v.z; tile[r][cg + 3] = v.w;
  }
  __syncthreads();
  int wx = t & 31, wy = t >> 5;  // r-pair, c-group
#pragma unroll
  for (int i = 0; i < 8; ++i) {
    int cl = wy + i * 8;
    unsigned int u = (unsigned int)f2bf(tile[2 * wx][cl]) |
                     ((unsigned int)f2bf(tile[2 * wx + 1][cl]) << 16);
    ((unsigned int*)(op + (size_t)(cb + cl) * R + rb))[wx] = u;
  }
}

// ---------------- gemm1: fused gate+up, 128(M)x64(N) tile ----------------
// LDS is chunk-major per 16-row slab: [slab][kchunk(4)][row(16)][8 halfs] so the
// fragment ds_read_b128 (16 rows, fixed kchunk) lands on banks 4*row%32 ->
// conflict-free minimum. Staging lane-map: chunk=lane>>4, row=lane&15 (global
// source is per-lane; LDS dest stays linear base+lane*16).
// Loop: double-buffered, issue next stage BEFORE compute, ONE __syncthreads
// per K-step (drain after MFMAs -> compute covers the load latency).
#define G1_STAGE(buf, kt2)                               \
    gload16(aptr0 + (kt2) * 32, &As[buf][aoff0]);        \
    gload16(aptr1 + (kt2) * 32, &As[buf][aoff1]);        \
    gload16(bgptr + (kt2) * 32, &Bgs[buf][boff]);        \
    gload16(buptr + (kt2) * 32, &Bus[buf][boff]);

#define G1_COMPUTE(buf)                                                         \
  {                                                                             \
    bf16x8 afr[4];                                                              \
    _Pragma("unroll") for (int i = 0; i < 4; ++i)                               \
      afr[i] = *(const bf16x8*)&As[buf][(wm * 4 + i) * 512 + chunk * 128 + rsub * 8]; \
    _Pragma("unroll") for (int j = 0; j < 2; ++j) {                             \
      bf16x8 bg = *(const bf16x8*)&Bgs[buf][(wn * 2 + j) * 512 + chunk * 128 + rsub * 8]; \
      bf16x8 bu = *(const bf16x8*)&Bus[buf][(wn * 2 + j) * 512 + chunk * 128 + rsub * 8]; \
      _Pragma("unroll") for (int i = 0; i < 4; ++i) {                           \
        accg[i][j] = __builtin_amdgcn_mfma_f32_16x16x32_bf16(afr[i], bg, accg[i][j], 0, 0, 0); \
        accu[i][j] = __builtin_amdgcn_mfma_f32_16x16x32_bf16(afr[i], bu, accu[i][j], 0, 0, 0); \
      }                                                                         \
    }                                                                           \
  }

__launch_bounds__(256, 3)
__global__ void gemm1_k(const unsigned short* __restrict__ Abase,
                        const int* __restrict__ rowlist,
                        const int* __restrict__ offs,
                        const int* __restrict__ tile_e, const int* __restrict__ tile_m,
                        int swz, int Mfixed,
                        const unsigned short* __restrict__ Bg_base,
                        const unsigned short* __restrict__ Bu_base,
                        int Ncols, int Kdim,
                        unsigned short* __restrict__ Out) {
  int e, mbase, Me, slotbase, nbase;
  if (swz) {
    int slot = blockIdx.x * CHUNK_CAP + (blockIdx.y & (CHUNK_CAP - 1));
    e = tile_e[slot];
    if (e < 0) return;
    mbase = tile_m[slot] * 128;
    slotbase = offs[e]; Me = offs[e + 1] - slotbase;
    nbase = (int)(blockIdx.y >> 3) * 64;
  } else {
    e = 0; mbase = blockIdx.x * 128; slotbase = 0; Me = Mfixed;
    nbase = blockIdx.y * 64;
  }
  const unsigned short* Bg = Bg_base + (size_t)e * Ncols * Kdim;
  const unsigned short* Bu = Bu_base + (size_t)e * Ncols * Kdim;

  __shared__ unsigned short As[2][128 * 32];
  __shared__ unsigned short Bgs[2][64 * 32];
  __shared__ unsigned short Bus[2][64 * 32];

  int t = threadIdx.x, lane = t & 63, wave = t >> 6;
  int wm = wave >> 1, wn = wave & 1;
  int chunk = lane >> 4, rsub = lane & 15;   // chunk-major staging map

  int g0 = mbase + wave * 32 + rsub;
  int g1 = g0 + 16;
  int src0, src1;
  if (rowlist) {
    src0 = rowlist[slotbase + ((g0 < Me) ? g0 : 0)];
    src1 = rowlist[slotbase + ((g1 < Me) ? g1 : 0)];
  } else {
    src0 = (g0 < Me) ? g0 : 0;
    src1 = (g1 < Me) ? g1 : 0;
  }
  const unsigned short* aptr0 = Abase + (size_t)src0 * Kdim + chunk * 8;
  const unsigned short* aptr1 = Abase + (size_t)src1 * Kdim + chunk * 8;
  unsigned int aoff0 = (unsigned)(wave * 2) * 512;
  unsigned int aoff1 = aoff0 + 512;
  int bn = nbase + wave * 16 + rsub;
  const unsigned short* bgptr = Bg + (size_t)bn * Kdim + chunk * 8;
  const unsigned short* buptr = Bu + (size_t)bn * Kdim + chunk * 8;
  unsigned int boff = (unsigned)wave * 512;

  f32x4 accg[4][2], accu[4][2];
#pragma unroll
  for (int i = 0; i < 4; ++i)
#pragma unroll
    for (int j = 0; j < 2; ++j) {
      accg[i][j] = f32x4{0.f, 0.f, 0.f, 0.f};
      accu[i][j] = f32x4{0.f, 0.f, 0.f, 0.f};
    }

  int nk = Kdim >> 5;  // even for all our K
  G1_STAGE(0, 0)
  __syncthreads();
  for (int kt = 0; kt < nk; kt += 2) {
    if (kt + 1 < nk) { G1_STAGE(1, kt + 1) }
    G1_COMPUTE(0)
    __syncthreads();
    if (kt + 2 < nk) { G1_STAGE(0, kt + 2) }
    G1_COMPUTE(1)
    __syncthreads();
  }

  int r0 = (lane >> 4) * 4, cn = lane & 15;
#pragma unroll
  for (int i = 0; i < 4; ++i) {
#pragma unroll
    for (int rr = 0; rr < 4; ++rr) {
      int grow = mbase + wm * 64 + i * 16 + r0 + rr;
      if (grow < Me) {
        size_t rbase = (size_t)(slotbase + grow) * Ncols + nbase;
#pragma unroll
        for (int j = 0; j < 2; ++j) {
          float g = accg[i][j][rr], u = accu[i][j][rr];
          float a = (g / (1.f + __expf(-g))) * u;
          Out[rbase + wn * 32 + j * 16 + cn] = f2bf(a);
        }
      }
    }
  }
}

// ---------------- gemm2: down GEMM, 128x128 tile, split-K; same LDS layout /
// loop structure; epilogue fuses combine: atomicAdd(out[token], w*acc) --------
#define G2_STAGE(buf, kt2)                               \
    gload16(aptr0 + (kt2) * 32, &As[buf][loff0]);        \
    gload16(aptr1 + (kt2) * 32, &As[buf][loff1]);        \
    gload16(bptr0 + (kt2) * 32, &Bs[buf][loff0]);        \
    gload16(bptr1 + (kt2) * 32, &Bs[buf][loff1]);

#define G2_COMPUTE(buf)                                                         \
  {                                                                             \
    bf16x8 afr[4];                                                              \
    _Pragma("unroll") for (int i = 0; i < 4; ++i)                               \
      afr[i] = *(const bf16x8*)&As[buf][(wm * 4 + i) * 512 + chunk * 128 + rsub * 8]; \
    _Pragma("unroll") for (int j = 0; j < 4; ++j) {                             \
      bf16x8 bb = *(const bf16x8*)&Bs[buf][(wn * 4 + j) * 512 + chunk * 128 + rsub * 8]; \
      _Pragma("unroll") for (int i = 0; i < 4; ++i)                             \
        acc[i][j] = __builtin_amdgcn_mfma_f32_16x16x32_bf16(afr[i], bb, acc[i][j], 0, 0, 0); \
    }                                                                           \
  }

__launch_bounds__(256, 3)
__global__ void gemm2_k(const unsigned short* __restrict__ Abase,
                        const int* __restrict__ rowlist,
                        const float* __restrict__ roww,
                        const int* __restrict__ offs,
                        const int* __restrict__ tile_e, const int* __restrict__ tile_m,
                        int swz, int Mfixed,
                        const unsigned short* __restrict__ Bt_base,  // [e][Ncols][Kdim]
                        int Ncols, int Kdim, int kchunk,
                        float* __restrict__ Out) {
  int e, mbase, Me, slotbase, nbase, koff;
  if (swz) {
    int slot = blockIdx.x * CHUNK_CAP + (blockIdx.y & (CHUNK_CAP - 1));
    e = tile_e[slot];
    if (e < 0) return;
    mbase = tile_m[slot] * 128;
    slotbase = offs[e]; Me = offs[e + 1] - slotbase;
    int r = blockIdx.y >> 3;       // 0..(nsplit*ntiles-1)
    nbase = (r & 7) * 128;
    koff = (r >> 3) * kchunk;
  } else {
    e = 0; mbase = blockIdx.x * 128; slotbase = 0; Me = Mfixed;
    nbase = blockIdx.y * 128;
    koff = blockIdx.z * kchunk;
  }
  const unsigned short* Bt = Bt_base + (size_t)e * Ncols * Kdim;

  __shared__ unsigned short As[2][128 * 32];
  __shared__ unsigned short Bs[2][128 * 32];

  int t = threadIdx.x, lane = t & 63, wave = t >> 6;
  int wm = wave >> 1, wn = wave & 1;
  int chunk = lane >> 4, rsub = lane & 15;   // chunk-major staging map

  int ra = wave * 32 + rsub, rb2 = ra + 16;
  int g0 = mbase + ra, g1 = mbase + rb2;
  int arow0 = slotbase + ((g0 < Me) ? g0 : 0);
  int arow1 = slotbase + ((g1 < Me) ? g1 : 0);
  const unsigned short* aptr0 = Abase + (size_t)arow0 * Kdim + koff + chunk * 8;
  const unsigned short* aptr1 = Abase + (size_t)arow1 * Kdim + koff + chunk * 8;
  const unsigned short* bptr0 = Bt + (size_t)(nbase + ra) * Kdim + koff + chunk * 8;
  const unsigned short* bptr1 = Bt + (size_t)(nbase + rb2) * Kdim + koff + chunk * 8;
  unsigned int loff0 = (unsigned)(wave * 2) * 512;
  unsigned int loff1 = loff0 + 512;

  f32x4 acc[4][4];
#pragma unroll
  for (int i = 0; i < 4; ++i)
#pragma unroll
    for (int j = 0; j < 4; ++j) acc[i][j] = f32x4{0.f, 0.f, 0.f, 0.f};

  int nk = kchunk >> 5;  // even for all our K
  G2_STAGE(0, 0)
  __syncthreads();
  for (int kt = 0; kt < nk; kt += 2) {
    if (kt + 1 < nk) { G2_STAGE(1, kt + 1) }
    G2_COMPUTE(0)
    __syncthreads();
    if (kt + 2 < nk) { G2_STAGE(0, kt + 2) }
    G2_COMPUTE(1)
    __syncthreads();
  }

  int er0 = (lane >> 4) * 4, cn = lane & 15;
#pragma unroll
  for (int i = 0; i < 4; ++i) {
#pragma unroll
    for (int rr = 0; rr < 4; ++rr) {
      int grow = mbase + wm * 64 + i * 16 + er0 + rr;
      if (grow < Me) {
        int srow = slotbase + grow;
        int token; float wgt;
        if (rowlist) { token = rowlist[srow]; wgt = roww[srow]; }
        else { token = grow; wgt = 1.f; }
        float* orow = Out + (size_t)token * Ncols + nbase + wn * 64 + cn;
#pragma unroll
        for (int j = 0; j < 4; ++j)
          atomicAdd(&orow[j * 16], wgt * acc[i][j][rr]);
      }
    }
  }
}

// ---------------- fallback (Round-1) GEMMs, used only if ws too small ----------------
__launch_bounds__(256, 2)
__global__ void gemm1_old(const unsigned short* __restrict__ Abase,
                          const int* __restrict__ rowlist,
                          const int* __restrict__ offs, int Mfixed,
                          const float* __restrict__ Bg_base,
                          const float* __restrict__ Bu_base,
                          int Ncols, int Kdim,
                          unsigned short* __restrict__ Out) {
  int e = blockIdx.z;
  int Me, slotbase;
  if (offs) { slotbase = offs[e]; Me = offs[e + 1] - slotbase; }
  else      { slotbase = 0;       Me = Mfixed; }
  int mbase = blockIdx.x * 128;
  if (mbase >= Me) return;
  int nbase = blockIdx.y * 128;
  const float* Bg = Bg_base + (size_t)e * Kdim * Ncols;
  const float* Bu = Bu_base + (size_t)e * Kdim * Ncols;
  __shared__ unsigned short As[128][40];
  __shared__ unsigned short Bgs[128][40];
  __shared__ unsigned short Bus[128][40];
  int t = threadIdx.x, lane = t & 63, wave = t >> 6;
  int wm = wave >> 1, wn = wave & 1;
  f32x4 accg[4][4], accu[4][4];
#pragma unroll
  for (int i = 0; i < 4; ++i)
#pragma unroll
    for (int j = 0; j < 4; ++j) {
      accg[i][j] = f32x4{0.f, 0.f, 0.f, 0.f};
      accu[i][j] = f32x4{0.f, 0.f, 0.f, 0.f};
    }
  int ar = t >> 1, akh = t & 1;
  int arow = mbase + ar;
  int asrc = 0;
  if (arow < Me) asrc = rowlist ? rowlist[slotbase + arow] : arow;
  const unsigned short* aptr = Abase + (size_t)asrc * Kdim + akh * 16;
  int bfc = t & 127, bkh = t >> 7;
  const float* bgp = Bg + (size_t)(bkh * 16) * Ncols + nbase + bfc;
  const float* bup = Bu + (size_t)(bkh * 16) * Ncols + nbase + bfc;
  int nk = Kdim >> 5;
  for (int kt = 0; kt < nk; ++kt) {
    uint4 a0 = *(const uint4*)(aptr + kt * 32);
    uint4 a1 = *(const uint4*)(aptr + kt * 32 + 8);
    *(uint4*)&As[ar][akh * 16] = a0;
    *(uint4*)&As[ar][akh * 16 + 8] = a1;
    {
      const float* p0 = bgp + (size_t)kt * 32 * Ncols;
      float bv[16]; unsigned short h[16];
#pragma unroll
      for (int i = 0; i < 16; ++i) bv[i] = p0[(size_t)i * Ncols];
#pragma unroll
      for (int i = 0; i < 16; ++i) h[i] = f2bf(bv[i]);
      *(uint4*)&Bgs[bfc][bkh * 16] = *(uint4*)&h[0];
      *(uint4*)&Bgs[bfc][bkh * 16 + 8] = *(uint4*)&h[8];
    }
    {
      const float* p1 = bup + (size_t)kt * 32 * Ncols;
      float bv[16]; unsigned short h[16];
#pragma unroll
      for (int i = 0; i < 16; ++i) bv[i] = p1[(size_t)i * Ncols];
#pragma unroll
      for (int i = 0; i < 16; ++i) h[i] = f2bf(bv[i]);
      *(uint4*)&Bus[bfc][bkh * 16] = *(uint4*)&h[0];
      *(uint4*)&Bus[bfc][bkh * 16 + 8] = *(uint4*)&h[8];
    }
    __syncthreads();
    bf16x8 afr[4];
#pragma unroll
    for (int i = 0; i < 4; ++i)
      afr[i] = *(const bf16x8*)&As[wm * 64 + i * 16 + (lane & 15)][(lane >> 4) * 8];
#pragma unroll
    for (int j = 0; j < 4; ++j) {
      bf16x8 bg = *(const bf16x8*)&Bgs[wn * 64 + j * 16 + (lane & 15)][(lane >> 4) * 8];
      bf16x8 bu = *(const bf16x8*)&Bus[wn * 64 + j * 16 + (lane & 15)][(lane >> 4) * 8];
#pragma unroll
      for (int i = 0; i < 4; ++i) {
        accg[i][j] = __builtin_amdgcn_mfma_f32_16x16x32_bf16(afr[i], bg, accg[i][j], 0, 0, 0);
        accu[i][j] = __builtin_amdgcn_mfma_f32_16x16x32_bf16(afr[i], bu, accu[i][j], 0, 0, 0);
      }
    }
    __syncthreads();
  }
  int r0 = (lane >> 4) * 4, cn = lane & 15;
#pragma unroll
  for (int i = 0; i < 4; ++i) {
#pragma unroll
    for (int rr = 0; rr < 4; ++rr) {
      int grow = mbase + wm * 64 + i * 16 + r0 + rr;
      if (grow < Me) {
        size_t rbase = (size_t)(slotbase + grow) * Ncols + nbase;
#pragma unroll
        for (int j = 0; j < 4; ++j) {
          float g = accg[i][j][rr], u = accu[i][j][rr];
          float a = (g / (1.f + __expf(-g))) * u;
          Out[rbase + wn * 64 + j * 16 + cn] = f2bf(a);
        }
      }
    }
  }
}

__launch_bounds__(256, 2)
__global__ void gemm2_old(const unsigned short* __restrict__ Abase,
                          const int* __restrict__ offs, int Mfixed,
                          const float* __restrict__ B_base,
                          int Ncols, int Kdim,
                          float* __restrict__ Out) {
  int e = blockIdx.z;
  int Me, slotbase;
  if (offs) { slotbase = offs[e]; Me = offs[e + 1] - slotbase; }
  else      { slotbase = 0;       Me = Mfixed; }
  int mbase = blockIdx.x * 128;
  if (mbase >= Me) return;
  int nbase = blockIdx.y * 128;
  const float* B = B_base + (size_t)e * Kdim * Ncols;
  __shared__ unsigned short As[128][40];
  __shared__ unsigned short Bs[128][40];
  int t = threadIdx.x, lane = t & 63, wave = t >> 6;
  int wm = wave >> 1, wn = wave & 1;
  f32x4 acc[4][4];
#pragma unroll
  for (int i = 0; i < 4; ++i)
#pragma unroll
    for (int j = 0; j < 4; ++j) acc[i][j] = f32x4{0.f, 0.f, 0.f, 0.f};
  int ar = t >> 1, akh = t & 1;
  int arow = slotbase + ((mbase + ar < Me) ? (mbase + ar) : 0);
  const unsigned short* aptr = Abase + (size_t)arow * Kdim + akh * 16;
  int bfc = t & 127, bkh = t >> 7;
  const float* bp = B + (size_t)(bkh * 16) * Ncols + nbase + bfc;
  int nk = Kdim >> 5;
  for (int kt = 0; kt < nk; ++kt) {
    uint4 a0 = *(const uint4*)(aptr + kt * 32);
    uint4 a1 = *(const uint4*)(aptr + kt * 32 + 8);
    *(uint4*)&As[ar][akh * 16] = a0;
    *(uint4*)&As[ar][akh * 16 + 8] = a1;
    {
      const float* p0 = bp + (size_t)kt * 32 * Ncols;
      float bv[16]; unsigned short h[16];
#pragma unroll
      for (int i = 0; i < 16; ++i) bv[i] = p0[(size_t)i * Ncols];
#pragma unroll
      for (int i = 0; i < 16; ++i) h[i] = f2bf(bv[i]);
      *(uint4*)&Bs[bfc][bkh * 16] = *(uint4*)&h[0];
      *(uint4*)&Bs[bfc][bkh * 16 + 8] = *(uint4*)&h[8];
    }
    __syncthreads();
    bf16x8 afr[4];
#pragma unroll
    for (int i = 0; i < 4; ++i)
      afr[i] = *(const bf16x8*)&As[wm * 64 + i * 16 + (lane & 15)][(lane >> 4) * 8];
#pragma unroll
    for (int j = 0; j < 4; ++j) {
      bf16x8 bb = *(const bf16x8*)&Bs[wn * 64 + j * 16 + (lane & 15)][(lane >> 4) * 8];
#pragma unroll
      for (int i = 0; i < 4; ++i)
        acc[i][j] = __builtin_amdgcn_mfma_f32_16x16x32_bf16(afr[i], bb, acc[i][j], 0, 0, 0);
    }
    __syncthreads();
  }
  int r0 = (lane >> 4) * 4, cn = lane & 15;
#pragma unroll
  for (int i = 0; i < 4; ++i) {
#pragma unroll
    for (int rr = 0; rr < 4; ++rr) {
      int grow = mbase + wm * 64 + i * 16 + r0 + rr;
      if (grow < Me) {
        size_t rbase = (size_t)(slotbase + grow) * Ncols + nbase;
#pragma unroll
        for (int j = 0; j < 4; ++j)
          Out[rbase + wn * 64 + j * 16 + cn] = acc[i][j][rr];
      }
    }
  }
}

__global__ void combine_k(const float* __restrict__ eo, const float* __restrict__ sh,
                          const float* __restrict__ topw, const int* __restrict__ slot_of,
                          float* __restrict__ out) {
  int idx = blockIdx.x * blockDim.x + threadIdx.x;
  int n = idx >> 8;
  int d4 = idx & 255;
  float w0 = topw[n * 2], w1 = topw[n * 2 + 1];
  int s0 = slot_of[n * 2], s1 = slot_of[n * 2 + 1];
  float4 a = ((const float4*)(eo + (size_t)s0 * D_))[d4];
  float4 b = ((const float4*)(eo + (size_t)s1 * D_))[d4];
  float4 c = ((const float4*)(sh + (size_t)n * D_))[d4];
  float4 r;
  r.x = w0 * a.x + w1 * b.x + c.x;
  r.y = w0 * a.y + w1 * b.y + c.y;
  r.z = w0 * a.z + w1 * b.z + c.z;
  r.w = w0 * a.w + w1 * b.w + c.w;
  ((float4*)out)[idx] = r;
}

extern "C" void kernel_launch(void* const* d_in, const int* in_sizes, int n_in,
                              void* d_out, int out_size, void* d_ws, size_t ws_size,
                              hipStream_t stream) {
  const float* x  = (const float*)d_in[0];
  const float* gw = (const float*)d_in[1];
  const float* gk = (const float*)d_in[2];
  const float* uk = (const float*)d_in[3];
  const float* dk = (const float*)d_in[4];
  const float* sg = (const float*)d_in[5];
  const float* su = (const float*)d_in[6];
  const float* sd = (const float*)d_in[7];
  float* out = (float*)d_out;

  char* w = (char*)d_ws;
  size_t o = 0;
  auto take = [&](size_t bytes) -> void* {
    void* p = w + o;
    o += (bytes + 255) & ~(size_t)255;
    return p;
  };
  // common buffers (fit in the Round-1 footprint)
  unsigned short* xbf    = (unsigned short*)take((size_t)N_ * D_ * 2);
  unsigned short* act    = (unsigned short*)take((size_t)ROWS_CAP * F_ * 2);
  unsigned short* act_sh = (unsigned short*)take((size_t)N_ * FS_ * 2);
  float* eo     = (float*)take((size_t)ROWS_CAP * D_ * 4);   // fallback only
  float* sh_out = (float*)take((size_t)N_ * D_ * 4);         // fallback only
  float* topw   = (float*)take((size_t)N_ * 2 * 4);
  int* topi     = (int*)take((size_t)N_ * 2 * 4);
  int* slot_of  = (int*)take((size_t)N_ * 2 * 4);
  int* rowlist  = (int*)take((size_t)ROWS_CAP * 4);
  int* counts   = (int*)take(E_ * 4);
  int* offs     = (int*)take((E_ + 1) * 4);
  int* cursor   = (int*)take(E_ * 4);
  int* tile_e   = (int*)take(NCHUNK * CHUNK_CAP * 4);
  int* tile_m   = (int*)take(NCHUNK * CHUNK_CAP * 4);
  // per-slot combine weight; alias onto eo (unused in full path, and in the
  // fallback path gemm2_old fully overwrites eo after fill_k runs).
  float* roww = eo;
  // full-path: bf16 transposed weights
  unsigned short* gkt = (unsigned short*)take((size_t)E_ * D_ * F_ * 2);
  unsigned short* ukt = (unsigned short*)take((size_t)E_ * D_ * F_ * 2);
  unsigned short* dkt = (unsigned short*)take((size_t)E_ * D_ * F_ * 2);
  unsigned short* sgt = (unsigned short*)take((size_t)D_ * FS_ * 2);
  unsigned short* sut = (unsigned short*)take((size_t)D_ * FS_ * 2);
  unsigned short* sdt = (unsigned short*)take((size_t)D_ * FS_ * 2);
  bool full = (ws_size >= o);

  hipLaunchKernelGGL(init_k, dim3(1), dim3(64), 0, stream, counts);
  hipLaunchKernelGGL(router_k, dim3(N_ / 4), dim3(256), 0, stream,
                     x, gw, xbf, topw, topi, counts);
  hipLaunchKernelGGL(scan_k, dim3(1), dim3(32), 0, stream,
                     counts, offs, cursor, tile_e, tile_m);
  hipLaunchKernelGGL(fill_k, dim3(N_ / 256), dim3(256), 0, stream,
                     topi, topw, offs, cursor, rowlist, slot_of, roww);

  if (full) {
    // weight transpose+convert: fp32 [R,C] -> bf16 [C,R]
    hipLaunchKernelGGL(transpose_cvt_k, dim3(F_ / 64, D_ / 64, E_), dim3(256), 0, stream,
                       gk, gkt, D_, F_);
    hipLaunchKernelGGL(transpose_cvt_k, dim3(F_ / 64, D_ / 64, E_), dim3(256), 0, stream,
                       uk, ukt, D_, F_);
    hipLaunchKernelGGL(transpose_cvt_k, dim3(D_ / 64, F_ / 64, E_), dim3(256), 0, stream,
                       dk, dkt, F_, D_);
    hipLaunchKernelGGL(transpose_cvt_k, dim3(FS_ / 64, D_ / 64, 1), dim3(256), 0, stream,
                       sg, sgt, D_, FS_);
    hipLaunchKernelGGL(transpose_cvt_k, dim3(FS_ / 64, D_ / 64, 1), dim3(256), 0, stream,
                       su, sut, D_, FS_);
    hipLaunchKernelGGL(transpose_cvt_k, dim3(D_ / 64, FS_ / 64, 1), dim3(256), 0, stream,
                       sd, sdt, FS_, D_);
    // output accumulator (gemm2 atomically adds routed*w + shared into it)
    hipMemsetAsync(out, 0, (size_t)N_ * D_ * 4, stream);
    // routed gate/up  — grid (chunk=XCD, slot*ntile)
    hipLaunchKernelGGL(gemm1_k, dim3(NCHUNK, CHUNK_CAP * (F_ / 64)), dim3(256), 0, stream,
                       xbf, rowlist, offs, tile_e, tile_m, 1, 0,
                       gkt, ukt, F_, D_, act);
    // shared gate/up
    hipLaunchKernelGGL(gemm1_k, dim3(N_ / 128, FS_ / 64), dim3(256), 0, stream,
                       xbf, (const int*)nullptr, (const int*)nullptr,
                       (const int*)nullptr, (const int*)nullptr, 0, N_,
                       sgt, sut, FS_, D_, act_sh);
    // routed down (split-K = 2), fused combine epilogue
    hipLaunchKernelGGL(gemm2_k, dim3(NCHUNK, CHUNK_CAP * (D_ / 128) * 2), dim3(256), 0, stream,
                       act, rowlist, roww, offs, tile_e, tile_m, 1, 0,
                       dkt, D_, F_, F_ / 2, out);
    // shared down (split-K = 2), adds into out
    hipLaunchKernelGGL(gemm2_k, dim3(N_ / 128, D_ / 128, 2), dim3(256), 0, stream,
                       act_sh, (const int*)nullptr, (const float*)nullptr,
                       (const int*)nullptr, (const int*)nullptr, (const int*)nullptr, 0, N_,
                       sdt, D_, FS_, FS_ / 2, out);
  } else {
    hipLaunchKernelGGL(gemm1_old, dim3(16, F_ / 128, E_), dim3(256), 0, stream,
                       xbf, rowlist, offs, 0, gk, uk, F_, D_, act);
    hipLaunchKernelGGL(gemm1_old, dim3(16, FS_ / 128, 1), dim3(256), 0, stream,
                       xbf, (const int*)nullptr, (const int*)nullptr, N_, sg, su, FS_, D_, act_sh);
    hipLaunchKernelGGL(gemm2_old, dim3(16, D_ / 128, E_), dim3(256), 0, stream,
                       act, offs, 0, dk, D_, F_, eo);
    hipLaunchKernelGGL(gemm2_old, dim3(16, D_ / 128, 1), dim3(256), 0, stream,
                       act_sh, (const int*)nullptr, N_, sd, D_, FS_, sh_out);
    hipLaunchKernelGGL(combine_k, dim3((N_ * D_ / 4) / 256), dim3(256), 0, stream,
                       eo, sh_out, topw, slot_of, out);
  }
}

// Round 3
// 794.450 us; speedup vs baseline: 1.1861x; 1.1861x over previous
//
#include <hip/hip_runtime.h>
#include <hip/hip_bf16.h>

#define E_ 8
#define K_ 2
#define D_ 1024
#define F_ 4096
#define FS_ 2048
#define N_ 2048
#define ROWS_CAP 4352
#define NCHUNK 8
#define CHUNK_CAP 8

typedef __bf16 bf16x8 __attribute__((ext_vector_type(8)));
typedef float f32x4 __attribute__((ext_vector_type(4)));

static __device__ __forceinline__ unsigned short f2bf(float f) {
  union { float f; unsigned int u; } v; v.f = f;
  unsigned int u = v.u;
  return (unsigned short)((u + 0x7FFF + ((u >> 16) & 1)) >> 16);  // RNE
}

// async global->LDS, 16B per lane; LDS dest = wave-uniform base + lane*16
static __device__ __forceinline__ void gload16(const unsigned short* gp, unsigned short* lp) {
  __builtin_amdgcn_global_load_lds(
      (const __attribute__((address_space(1))) unsigned int*)gp,
      (__attribute__((address_space(3))) unsigned int*)lp, 16, 0, 0);
}

__global__ void init_k(int* counts) {
  if (threadIdx.x < E_) counts[threadIdx.x] = 0;
}

// One wave per token: logits, softmax, top-2, counts; casts x row to bf16.
__global__ void router_k(const float* __restrict__ x, const float* __restrict__ gw,
                         unsigned short* __restrict__ xbf, float* __restrict__ topw,
                         int* __restrict__ topi, int* __restrict__ counts) {
  int wave = threadIdx.x >> 6, lane = threadIdx.x & 63;
  int n = blockIdx.x * 4 + wave;
  const float* xr = x + (size_t)n * D_;
  float v[16];
#pragma unroll
  for (int j = 0; j < 16; ++j) v[j] = xr[lane + 64 * j];
#pragma unroll
  for (int j = 0; j < 16; ++j) xbf[(size_t)n * D_ + lane + 64 * j] = f2bf(v[j]);
  float logit[E_];
  for (int e = 0; e < E_; ++e) {
    const float* g = gw + e * D_;
    float acc = 0.f;
#pragma unroll
    for (int j = 0; j < 16; ++j) acc += v[j] * g[lane + 64 * j];
#pragma unroll
    for (int off = 32; off > 0; off >>= 1) acc += __shfl_down(acc, off, 64);
    logit[e] = __shfl(acc, 0, 64);
  }
  if (lane == 0) {
    float m = logit[0];
    for (int e = 1; e < E_; ++e) m = fmaxf(m, logit[e]);
    float p[E_], s = 0.f;
    for (int e = 0; e < E_; ++e) { p[e] = expf(logit[e] - m); s += p[e]; }
    float inv = 1.f / s;
    for (int e = 0; e < E_; ++e) p[e] *= inv;
    int i0 = 0;
    for (int e = 1; e < E_; ++e) if (p[e] > p[i0]) i0 = e;
    int i1 = (i0 == 0) ? 1 : 0;
    for (int e = 0; e < E_; ++e) if (e != i0 && p[e] > p[i1]) i1 = e;
    topi[n * 2] = i0; topi[n * 2 + 1] = i1;
    topw[n * 2] = p[i0]; topw[n * 2 + 1] = p[i1];
    atomicAdd(&counts[i0], 1);
    atomicAdd(&counts[i1], 1);
  }
}

// prefix sum + XCD-chunked (expert, mtile) table: each expert's tiles are
// binned into one of 8 chunks (least-loaded greedy) so all M-tiles that share
// a weight panel run on the SAME XCD (gridDim.x==8 -> flat%8 == chunk).
__global__ void scan_k(const int* __restrict__ counts, int* __restrict__ offs,
                       int* __restrict__ cursor, int* __restrict__ tile_e,
                       int* __restrict__ tile_m) {
  if (threadIdx.x == 0) {
    int load[NCHUNK];
    for (int c = 0; c < NCHUNK; ++c) load[c] = 0;
    for (int i = 0; i < NCHUNK * CHUNK_CAP; ++i) tile_e[i] = -1;
    int o = 0;
    for (int e = 0; e < E_; ++e) {
      offs[e] = o;
      int c = counts[e];
      int mt = (c + 127) >> 7;
      int best = 0;
      for (int c2 = 1; c2 < NCHUNK; ++c2) if (load[c2] < load[best]) best = c2;
      for (int m = 0; m < mt; ++m) {
        int ch = best;
        if (load[ch] >= CHUNK_CAP) {
          ch = 0;
          for (int c2 = 1; c2 < NCHUNK; ++c2) if (load[c2] < load[ch]) ch = c2;
        }
        tile_e[ch * CHUNK_CAP + load[ch]] = e;
        tile_m[ch * CHUNK_CAP + load[ch]] = m;
        load[ch]++;
      }
      o += c; cursor[e] = 0;
    }
    offs[E_] = o;
  }
}

__global__ void fill_k(const int* __restrict__ topi, const float* __restrict__ topw,
                       const int* __restrict__ offs,
                       int* __restrict__ cursor, int* __restrict__ rowlist,
                       int* __restrict__ slot_of, float* __restrict__ roww) {
  int n = blockIdx.x * blockDim.x + threadIdx.x;
  if (n >= N_) return;
  for (int k = 0; k < K_; ++k) {
    int e = topi[n * 2 + k];
    int pos = offs[e] + atomicAdd(&cursor[e], 1);
    rowlist[pos] = n;
    slot_of[n * 2 + k] = pos;
    roww[pos] = topw[n * 2 + k];
  }
}

// fp32 [R,C] -> bf16 [C,R] (per batch z). float4 loads, coalesced both sides.
__global__ void transpose_cvt_k(const float* __restrict__ in, unsigned short* __restrict__ out,
                                int R, int C) {
  __shared__ float tile[64][65];
  int cb = blockIdx.x * 64, rb = blockIdx.y * 64;
  const float* ip = in + (size_t)blockIdx.z * R * C;
  unsigned short* op = out + (size_t)blockIdx.z * R * C;
  int t = threadIdx.x;
  int cg = (t & 15) * 4, r0 = t >> 4;
#pragma unroll
  for (int p = 0; p < 4; ++p) {
    int r = r0 + p * 16;
    float4 v = *(const float4*)&ip[(size_t)(rb + r) * C + cb + cg];
    tile[r][cg] = v.x; tile[r][cg + 1] = v.y; tile[r][cg + 2] = v.z; tile[r][cg + 3] = v.w;
  }
  __syncthreads();
  int wx = t & 31, wy = t >> 5;  // r-pair, c-group
#pragma unroll
  for (int i = 0; i < 8; ++i) {
    int cl = wy + i * 8;
    unsigned int u = (unsigned int)f2bf(tile[2 * wx][cl]) |
                     ((unsigned int)f2bf(tile[2 * wx + 1][cl]) << 16);
    ((unsigned int*)(op + (size_t)(cb + cl) * R + rb))[wx] = u;
  }
}

// ---------------- gemm1: fused gate+up, 128(M)x64(N) tile, R0 structure ------
// Single-buffer LDS (16 KB), row-major [row][32] staging (chunk=lane&3),
// stage -> sync -> compute -> sync per K-step. 4 blocks/CU via launch_bounds.
__launch_bounds__(256, 4)
__global__ void gemm1_k(const unsigned short* __restrict__ Abase,
                        const int* __restrict__ rowlist,
                        const int* __restrict__ offs,
                        const int* __restrict__ tile_e, const int* __restrict__ tile_m,
                        int swz, int Mfixed,
                        const unsigned short* __restrict__ Bg_base,
                        const unsigned short* __restrict__ Bu_base,
                        int Ncols, int Kdim,
                        unsigned short* __restrict__ Out) {
  int e, mbase, Me, slotbase, nbase;
  if (swz) {
    int slot = blockIdx.x * CHUNK_CAP + (blockIdx.y & (CHUNK_CAP - 1));
    e = tile_e[slot];
    if (e < 0) return;
    mbase = tile_m[slot] * 128;
    slotbase = offs[e]; Me = offs[e + 1] - slotbase;
    nbase = (int)(blockIdx.y >> 3) * 64;
  } else {
    e = 0; mbase = blockIdx.x * 128; slotbase = 0; Me = Mfixed;
    nbase = blockIdx.y * 64;
  }
  const unsigned short* Bg = Bg_base + (size_t)e * Ncols * Kdim;
  const unsigned short* Bu = Bu_base + (size_t)e * Ncols * Kdim;

  __shared__ unsigned short As[128 * 32];
  __shared__ unsigned short Bgs[64 * 32];
  __shared__ unsigned short Bus[64 * 32];

  int t = threadIdx.x, lane = t & 63, wave = t >> 6;
  int wm = wave >> 1, wn = wave & 1;
  int chunk = lane & 3, rsub = lane >> 2;

  const unsigned short* aptr[2];
  unsigned int aoff[2];
#pragma unroll
  for (int i = 0; i < 2; ++i) {
    int r = wave * 32 + i * 16 + rsub;
    int grow = mbase + r;
    int src;
    if (rowlist) src = rowlist[slotbase + ((grow < Me) ? grow : 0)];
    else src = (grow < Me) ? grow : 0;
    aptr[i] = Abase + (size_t)src * Kdim + chunk * 8;
    aoff[i] = (unsigned)(wave * 32 + i * 16) * 32;
  }
  int bn = nbase + wave * 16 + rsub;
  const unsigned short* bgptr = Bg + (size_t)bn * Kdim + chunk * 8;
  const unsigned short* buptr = Bu + (size_t)bn * Kdim + chunk * 8;
  unsigned int boff = (unsigned)(wave * 16) * 32;

  f32x4 accg[4][2], accu[4][2];
#pragma unroll
  for (int i = 0; i < 4; ++i)
#pragma unroll
    for (int j = 0; j < 2; ++j) {
      accg[i][j] = f32x4{0.f, 0.f, 0.f, 0.f};
      accu[i][j] = f32x4{0.f, 0.f, 0.f, 0.f};
    }

  int nk = Kdim >> 5;
  for (int kt = 0; kt < nk; ++kt) {
    gload16(aptr[0] + kt * 32, &As[aoff[0]]);
    gload16(aptr[1] + kt * 32, &As[aoff[1]]);
    gload16(bgptr + kt * 32, &Bgs[boff]);
    gload16(buptr + kt * 32, &Bus[boff]);
    __syncthreads();
    bf16x8 afr[4];
#pragma unroll
    for (int i = 0; i < 4; ++i)
      afr[i] = *(const bf16x8*)&As[(wm * 64 + i * 16 + (lane & 15)) * 32 + (lane >> 4) * 8];
#pragma unroll
    for (int j = 0; j < 2; ++j) {
      bf16x8 bg = *(const bf16x8*)&Bgs[(wn * 32 + j * 16 + (lane & 15)) * 32 + (lane >> 4) * 8];
      bf16x8 bu = *(const bf16x8*)&Bus[(wn * 32 + j * 16 + (lane & 15)) * 32 + (lane >> 4) * 8];
#pragma unroll
      for (int i = 0; i < 4; ++i) {
        accg[i][j] = __builtin_amdgcn_mfma_f32_16x16x32_bf16(afr[i], bg, accg[i][j], 0, 0, 0);
        accu[i][j] = __builtin_amdgcn_mfma_f32_16x16x32_bf16(afr[i], bu, accu[i][j], 0, 0, 0);
      }
    }
    __syncthreads();
  }
  int r0 = (lane >> 4) * 4, cn = lane & 15;
#pragma unroll
  for (int i = 0; i < 4; ++i) {
#pragma unroll
    for (int rr = 0; rr < 4; ++rr) {
      int grow = mbase + wm * 64 + i * 16 + r0 + rr;
      if (grow < Me) {
        size_t rbase = (size_t)(slotbase + grow) * Ncols + nbase;
#pragma unroll
        for (int j = 0; j < 2; ++j) {
          float g = accg[i][j][rr], u = accu[i][j][rr];
          float a = (g / (1.f + __expf(-g))) * u;
          Out[rbase + wn * 32 + j * 16 + cn] = f2bf(a);
        }
      }
    }
  }
}

// ---------------- gemm2: down GEMM, 128x128, split-K, R0 structure; epilogue
// fuses combine: atomicAdd(out[token], w*acc) (routed) / +acc (shared) --------
__launch_bounds__(256, 4)
__global__ void gemm2_k(const unsigned short* __restrict__ Abase,
                        const int* __restrict__ rowlist,
                        const float* __restrict__ roww,
                        const int* __restrict__ offs,
                        const int* __restrict__ tile_e, const int* __restrict__ tile_m,
                        int swz, int Mfixed,
                        const unsigned short* __restrict__ Bt_base,  // [e][Ncols][Kdim]
                        int Ncols, int Kdim, int kchunk,
                        float* __restrict__ Out) {
  int e, mbase, Me, slotbase, nbase, koff;
  if (swz) {
    int slot = blockIdx.x * CHUNK_CAP + (blockIdx.y & (CHUNK_CAP - 1));
    e = tile_e[slot];
    if (e < 0) return;
    mbase = tile_m[slot] * 128;
    slotbase = offs[e]; Me = offs[e + 1] - slotbase;
    int r = blockIdx.y >> 3;       // 0..(nsplit*ntiles-1)
    nbase = (r & 7) * 128;
    koff = (r >> 3) * kchunk;
  } else {
    e = 0; mbase = blockIdx.x * 128; slotbase = 0; Me = Mfixed;
    nbase = blockIdx.y * 128;
    koff = blockIdx.z * kchunk;
  }
  const unsigned short* Bt = Bt_base + (size_t)e * Ncols * Kdim;

  __shared__ unsigned short As[128 * 32];
  __shared__ unsigned short Bs[128 * 32];

  int t = threadIdx.x, lane = t & 63, wave = t >> 6;
  int wm = wave >> 1, wn = wave & 1;
  int chunk = lane & 3, rsub = lane >> 2;

  const unsigned short* aptr[2];
  const unsigned short* bptr[2];
  unsigned int loff[2];
#pragma unroll
  for (int i = 0; i < 2; ++i) {
    int r = wave * 32 + i * 16 + rsub;
    int grow = mbase + r;
    int arow = slotbase + ((grow < Me) ? grow : 0);
    aptr[i] = Abase + (size_t)arow * Kdim + koff + chunk * 8;
    bptr[i] = Bt + (size_t)(nbase + r) * Kdim + koff + chunk * 8;
    loff[i] = (unsigned)(wave * 32 + i * 16) * 32;
  }

  f32x4 acc[4][4];
#pragma unroll
  for (int i = 0; i < 4; ++i)
#pragma unroll
    for (int j = 0; j < 4; ++j) acc[i][j] = f32x4{0.f, 0.f, 0.f, 0.f};

  int nk = kchunk >> 5;
  for (int kt = 0; kt < nk; ++kt) {
    gload16(aptr[0] + kt * 32, &As[loff[0]]);
    gload16(aptr[1] + kt * 32, &As[loff[1]]);
    gload16(bptr[0] + kt * 32, &Bs[loff[0]]);
    gload16(bptr[1] + kt * 32, &Bs[loff[1]]);
    __syncthreads();
    bf16x8 afr[4];
#pragma unroll
    for (int i = 0; i < 4; ++i)
      afr[i] = *(const bf16x8*)&As[(wm * 64 + i * 16 + (lane & 15)) * 32 + (lane >> 4) * 8];
#pragma unroll
    for (int j = 0; j < 4; ++j) {
      bf16x8 bb = *(const bf16x8*)&Bs[(wn * 64 + j * 16 + (lane & 15)) * 32 + (lane >> 4) * 8];
#pragma unroll
      for (int i = 0; i < 4; ++i)
        acc[i][j] = __builtin_amdgcn_mfma_f32_16x16x32_bf16(afr[i], bb, acc[i][j], 0, 0, 0);
    }
    __syncthreads();
  }
  int er0 = (lane >> 4) * 4, cn = lane & 15;
#pragma unroll
  for (int i = 0; i < 4; ++i) {
#pragma unroll
    for (int rr = 0; rr < 4; ++rr) {
      int grow = mbase + wm * 64 + i * 16 + er0 + rr;
      if (grow < Me) {
        int srow = slotbase + grow;
        int token; float wgt;
        if (rowlist) { token = rowlist[srow]; wgt = roww[srow]; }
        else { token = grow; wgt = 1.f; }
        float* orow = Out + (size_t)token * Ncols + nbase + wn * 64 + cn;
#pragma unroll
        for (int j = 0; j < 4; ++j)
          atomicAdd(&orow[j * 16], wgt * acc[i][j][rr]);
      }
    }
  }
}

// ---------------- fallback (Round-1) GEMMs, used only if ws too small ----------------
__launch_bounds__(256, 2)
__global__ void gemm1_old(const unsigned short* __restrict__ Abase,
                          const int* __restrict__ rowlist,
                          const int* __restrict__ offs, int Mfixed,
                          const float* __restrict__ Bg_base,
                          const float* __restrict__ Bu_base,
                          int Ncols, int Kdim,
                          unsigned short* __restrict__ Out) {
  int e = blockIdx.z;
  int Me, slotbase;
  if (offs) { slotbase = offs[e]; Me = offs[e + 1] - slotbase; }
  else      { slotbase = 0;       Me = Mfixed; }
  int mbase = blockIdx.x * 128;
  if (mbase >= Me) return;
  int nbase = blockIdx.y * 128;
  const float* Bg = Bg_base + (size_t)e * Kdim * Ncols;
  const float* Bu = Bu_base + (size_t)e * Kdim * Ncols;
  __shared__ unsigned short As[128][40];
  __shared__ unsigned short Bgs[128][40];
  __shared__ unsigned short Bus[128][40];
  int t = threadIdx.x, lane = t & 63, wave = t >> 6;
  int wm = wave >> 1, wn = wave & 1;
  f32x4 accg[4][4], accu[4][4];
#pragma unroll
  for (int i = 0; i < 4; ++i)
#pragma unroll
    for (int j = 0; j < 4; ++j) {
      accg[i][j] = f32x4{0.f, 0.f, 0.f, 0.f};
      accu[i][j] = f32x4{0.f, 0.f, 0.f, 0.f};
    }
  int ar = t >> 1, akh = t & 1;
  int arow = mbase + ar;
  int asrc = 0;
  if (arow < Me) asrc = rowlist ? rowlist[slotbase + arow] : arow;
  const unsigned short* aptr = Abase + (size_t)asrc * Kdim + akh * 16;
  int bfc = t & 127, bkh = t >> 7;
  const float* bgp = Bg + (size_t)(bkh * 16) * Ncols + nbase + bfc;
  const float* bup = Bu + (size_t)(bkh * 16) * Ncols + nbase + bfc;
  int nk = Kdim >> 5;
  for (int kt = 0; kt < nk; ++kt) {
    uint4 a0 = *(const uint4*)(aptr + kt * 32);
    uint4 a1 = *(const uint4*)(aptr + kt * 32 + 8);
    *(uint4*)&As[ar][akh * 16] = a0;
    *(uint4*)&As[ar][akh * 16 + 8] = a1;
    {
      const float* p0 = bgp + (size_t)kt * 32 * Ncols;
      float bv[16]; unsigned short h[16];
#pragma unroll
      for (int i = 0; i < 16; ++i) bv[i] = p0[(size_t)i * Ncols];
#pragma unroll
      for (int i = 0; i < 16; ++i) h[i] = f2bf(bv[i]);
      *(uint4*)&Bgs[bfc][bkh * 16] = *(uint4*)&h[0];
      *(uint4*)&Bgs[bfc][bkh * 16 + 8] = *(uint4*)&h[8];
    }
    {
      const float* p1 = bup + (size_t)kt * 32 * Ncols;
      float bv[16]; unsigned short h[16];
#pragma unroll
      for (int i = 0; i < 16; ++i) bv[i] = p1[(size_t)i * Ncols];
#pragma unroll
      for (int i = 0; i < 16; ++i) h[i] = f2bf(bv[i]);
      *(uint4*)&Bus[bfc][bkh * 16] = *(uint4*)&h[0];
      *(uint4*)&Bus[bfc][bkh * 16 + 8] = *(uint4*)&h[8];
    }
    __syncthreads();
    bf16x8 afr[4];
#pragma unroll
    for (int i = 0; i < 4; ++i)
      afr[i] = *(const bf16x8*)&As[wm * 64 + i * 16 + (lane & 15)][(lane >> 4) * 8];
#pragma unroll
    for (int j = 0; j < 4; ++j) {
      bf16x8 bg = *(const bf16x8*)&Bgs[wn * 64 + j * 16 + (lane & 15)][(lane >> 4) * 8];
      bf16x8 bu = *(const bf16x8*)&Bus[wn * 64 + j * 16 + (lane & 15)][(lane >> 4) * 8];
#pragma unroll
      for (int i = 0; i < 4; ++i) {
        accg[i][j] = __builtin_amdgcn_mfma_f32_16x16x32_bf16(afr[i], bg, accg[i][j], 0, 0, 0);
        accu[i][j] = __builtin_amdgcn_mfma_f32_16x16x32_bf16(afr[i], bu, accu[i][j], 0, 0, 0);
      }
    }
    __syncthreads();
  }
  int r0 = (lane >> 4) * 4, cn = lane & 15;
#pragma unroll
  for (int i = 0; i < 4; ++i) {
#pragma unroll
    for (int rr = 0; rr < 4; ++rr) {
      int grow = mbase + wm * 64 + i * 16 + r0 + rr;
      if (grow < Me) {
        size_t rbase = (size_t)(slotbase + grow) * Ncols + nbase;
#pragma unroll
        for (int j = 0; j < 4; ++j) {
          float g = accg[i][j][rr], u = accu[i][j][rr];
          float a = (g / (1.f + __expf(-g))) * u;
          Out[rbase + wn * 64 + j * 16 + cn] = f2bf(a);
        }
      }
    }
  }
}

__launch_bounds__(256, 2)
__global__ void gemm2_old(const unsigned short* __restrict__ Abase,
                          const int* __restrict__ offs, int Mfixed,
                          const float* __restrict__ B_base,
                          int Ncols, int Kdim,
                          float* __restrict__ Out) {
  int e = blockIdx.z;
  int Me, slotbase;
  if (offs) { slotbase = offs[e]; Me = offs[e + 1] - slotbase; }
  else      { slotbase = 0;       Me = Mfixed; }
  int mbase = blockIdx.x * 128;
  if (mbase >= Me) return;
  int nbase = blockIdx.y * 128;
  const float* B = B_base + (size_t)e * Kdim * Ncols;
  __shared__ unsigned short As[128][40];
  __shared__ unsigned short Bs[128][40];
  int t = threadIdx.x, lane = t & 63, wave = t >> 6;
  int wm = wave >> 1, wn = wave & 1;
  f32x4 acc[4][4];
#pragma unroll
  for (int i = 0; i < 4; ++i)
#pragma unroll
    for (int j = 0; j < 4; ++j) acc[i][j] = f32x4{0.f, 0.f, 0.f, 0.f};
  int ar = t >> 1, akh = t & 1;
  int arow = slotbase + ((mbase + ar < Me) ? (mbase + ar) : 0);
  const unsigned short* aptr = Abase + (size_t)arow * Kdim + akh * 16;
  int bfc = t & 127, bkh = t >> 7;
  const float* bp = B + (size_t)(bkh * 16) * Ncols + nbase + bfc;
  int nk = Kdim >> 5;
  for (int kt = 0; kt < nk; ++kt) {
    uint4 a0 = *(const uint4*)(aptr + kt * 32);
    uint4 a1 = *(const uint4*)(aptr + kt * 32 + 8);
    *(uint4*)&As[ar][akh * 16] = a0;
    *(uint4*)&As[ar][akh * 16 + 8] = a1;
    {
      const float* p0 = bp + (size_t)kt * 32 * Ncols;
      float bv[16]; unsigned short h[16];
#pragma unroll
      for (int i = 0; i < 16; ++i) bv[i] = p0[(size_t)i * Ncols];
#pragma unroll
      for (int i = 0; i < 16; ++i) h[i] = f2bf(bv[i]);
      *(uint4*)&Bs[bfc][bkh * 16] = *(uint4*)&h[0];
      *(uint4*)&Bs[bfc][bkh * 16 + 8] = *(uint4*)&h[8];
    }
    __syncthreads();
    bf16x8 afr[4];
#pragma unroll
    for (int i = 0; i < 4; ++i)
      afr[i] = *(const bf16x8*)&As[wm * 64 + i * 16 + (lane & 15)][(lane >> 4) * 8];
#pragma unroll
    for (int j = 0; j < 4; ++j) {
      bf16x8 bb = *(const bf16x8*)&Bs[wn * 64 + j * 16 + (lane & 15)][(lane >> 4) * 8];
#pragma unroll
      for (int i = 0; i < 4; ++i)
        acc[i][j] = __builtin_amdgcn_mfma_f32_16x16x32_bf16(afr[i], bb, acc[i][j], 0, 0, 0);
    }
    __syncthreads();
  }
  int r0 = (lane >> 4) * 4, cn = lane & 15;
#pragma unroll
  for (int i = 0; i < 4; ++i) {
#pragma unroll
    for (int rr = 0; rr < 4; ++rr) {
      int grow = mbase + wm * 64 + i * 16 + r0 + rr;
      if (grow < Me) {
        size_t rbase = (size_t)(slotbase + grow) * Ncols + nbase;
#pragma unroll
        for (int j = 0; j < 4; ++j)
          Out[rbase + wn * 64 + j * 16 + cn] = acc[i][j][rr];
      }
    }
  }
}

__global__ void combine_k(const float* __restrict__ eo, const float* __restrict__ sh,
                          const float* __restrict__ topw, const int* __restrict__ slot_of,
                          float* __restrict__ out) {
  int idx = blockIdx.x * blockDim.x + threadIdx.x;
  int n = idx >> 8;
  int d4 = idx & 255;
  float w0 = topw[n * 2], w1 = topw[n * 2 + 1];
  int s0 = slot_of[n * 2], s1 = slot_of[n * 2 + 1];
  float4 a = ((const float4*)(eo + (size_t)s0 * D_))[d4];
  float4 b = ((const float4*)(eo + (size_t)s1 * D_))[d4];
  float4 c = ((const float4*)(sh + (size_t)n * D_))[d4];
  float4 r;
  r.x = w0 * a.x + w1 * b.x + c.x;
  r.y = w0 * a.y + w1 * b.y + c.y;
  r.z = w0 * a.z + w1 * b.z + c.z;
  r.w = w0 * a.w + w1 * b.w + c.w;
  ((float4*)out)[idx] = r;
}

extern "C" void kernel_launch(void* const* d_in, const int* in_sizes, int n_in,
                              void* d_out, int out_size, void* d_ws, size_t ws_size,
                              hipStream_t stream) {
  const float* x  = (const float*)d_in[0];
  const float* gw = (const float*)d_in[1];
  const float* gk = (const float*)d_in[2];
  const float* uk = (const float*)d_in[3];
  const float* dk = (const float*)d_in[4];
  const float* sg = (const float*)d_in[5];
  const float* su = (const float*)d_in[6];
  const float* sd = (const float*)d_in[7];
  float* out = (float*)d_out;

  char* w = (char*)d_ws;
  size_t o = 0;
  auto take = [&](size_t bytes) -> void* {
    void* p = w + o;
    o += (bytes + 255) & ~(size_t)255;
    return p;
  };
  // common buffers (fit in the Round-1 footprint)
  unsigned short* xbf    = (unsigned short*)take((size_t)N_ * D_ * 2);
  unsigned short* act    = (unsigned short*)take((size_t)ROWS_CAP * F_ * 2);
  unsigned short* act_sh = (unsigned short*)take((size_t)N_ * FS_ * 2);
  float* eo     = (float*)take((size_t)ROWS_CAP * D_ * 4);   // fallback only
  float* sh_out = (float*)take((size_t)N_ * D_ * 4);         // fallback only
  float* topw   = (float*)take((size_t)N_ * 2 * 4);
  int* topi     = (int*)take((size_t)N_ * 2 * 4);
  int* slot_of  = (int*)take((size_t)N_ * 2 * 4);
  int* rowlist  = (int*)take((size_t)ROWS_CAP * 4);
  int* counts   = (int*)take(E_ * 4);
  int* offs     = (int*)take((E_ + 1) * 4);
  int* cursor   = (int*)take(E_ * 4);
  int* tile_e   = (int*)take(NCHUNK * CHUNK_CAP * 4);
  int* tile_m   = (int*)take(NCHUNK * CHUNK_CAP * 4);
  // per-slot combine weight; alias onto eo (unused in full path, and in the
  // fallback path gemm2_old fully overwrites eo after fill_k runs).
  float* roww = eo;
  // full-path: bf16 transposed weights
  unsigned short* gkt = (unsigned short*)take((size_t)E_ * D_ * F_ * 2);
  unsigned short* ukt = (unsigned short*)take((size_t)E_ * D_ * F_ * 2);
  unsigned short* dkt = (unsigned short*)take((size_t)E_ * D_ * F_ * 2);
  unsigned short* sgt = (unsigned short*)take((size_t)D_ * FS_ * 2);
  unsigned short* sut = (unsigned short*)take((size_t)D_ * FS_ * 2);
  unsigned short* sdt = (unsigned short*)take((size_t)D_ * FS_ * 2);
  bool full = (ws_size >= o);

  hipLaunchKernelGGL(init_k, dim3(1), dim3(64), 0, stream, counts);
  hipLaunchKernelGGL(router_k, dim3(N_ / 4), dim3(256), 0, stream,
                     x, gw, xbf, topw, topi, counts);
  hipLaunchKernelGGL(scan_k, dim3(1), dim3(32), 0, stream,
                     counts, offs, cursor, tile_e, tile_m);
  hipLaunchKernelGGL(fill_k, dim3(N_ / 256), dim3(256), 0, stream,
                     topi, topw, offs, cursor, rowlist, slot_of, roww);

  if (full) {
    // weight transpose+convert: fp32 [R,C] -> bf16 [C,R]
    hipLaunchKernelGGL(transpose_cvt_k, dim3(F_ / 64, D_ / 64, E_), dim3(256), 0, stream,
                       gk, gkt, D_, F_);
    hipLaunchKernelGGL(transpose_cvt_k, dim3(F_ / 64, D_ / 64, E_), dim3(256), 0, stream,
                       uk, ukt, D_, F_);
    hipLaunchKernelGGL(transpose_cvt_k, dim3(D_ / 64, F_ / 64, E_), dim3(256), 0, stream,
                       dk, dkt, F_, D_);
    hipLaunchKernelGGL(transpose_cvt_k, dim3(FS_ / 64, D_ / 64, 1), dim3(256), 0, stream,
                       sg, sgt, D_, FS_);
    hipLaunchKernelGGL(transpose_cvt_k, dim3(FS_ / 64, D_ / 64, 1), dim3(256), 0, stream,
                       su, sut, D_, FS_);
    hipLaunchKernelGGL(transpose_cvt_k, dim3(D_ / 64, FS_ / 64, 1), dim3(256), 0, stream,
                       sd, sdt, FS_, D_);
    // output accumulator (gemm2 atomically adds routed*w + shared into it)
    hipMemsetAsync(out, 0, (size_t)N_ * D_ * 4, stream);
    // routed gate/up  — grid (chunk=XCD, slot*ntile)
    hipLaunchKernelGGL(gemm1_k, dim3(NCHUNK, CHUNK_CAP * (F_ / 64)), dim3(256), 0, stream,
                       xbf, rowlist, offs, tile_e, tile_m, 1, 0,
                       gkt, ukt, F_, D_, act);
    // shared gate/up
    hipLaunchKernelGGL(gemm1_k, dim3(N_ / 128, FS_ / 64), dim3(256), 0, stream,
                       xbf, (const int*)nullptr, (const int*)nullptr,
                       (const int*)nullptr, (const int*)nullptr, 0, N_,
                       sgt, sut, FS_, D_, act_sh);
    // routed down (split-K = 2), fused combine epilogue
    hipLaunchKernelGGL(gemm2_k, dim3(NCHUNK, CHUNK_CAP * (D_ / 128) * 2), dim3(256), 0, stream,
                       act, rowlist, roww, offs, tile_e, tile_m, 1, 0,
                       dkt, D_, F_, F_ / 2, out);
    // shared down (split-K = 2), adds into out
    hipLaunchKernelGGL(gemm2_k, dim3(N_ / 128, D_ / 128, 2), dim3(256), 0, stream,
                       act_sh, (const int*)nullptr, (const float*)nullptr,
                       (const int*)nullptr, (const int*)nullptr, (const int*)nullptr, 0, N_,
                       sdt, D_, FS_, FS_ / 2, out);
  } else {
    hipLaunchKernelGGL(gemm1_old, dim3(16, F_ / 128, E_), dim3(256), 0, stream,
                       xbf, rowlist, offs, 0, gk, uk, F_, D_, act);
    hipLaunchKernelGGL(gemm1_old, dim3(16, FS_ / 128, 1), dim3(256), 0, stream,
                       xbf, (const int*)nullptr, (const int*)nullptr, N_, sg, su, FS_, D_, act_sh);
    hipLaunchKernelGGL(gemm2_old, dim3(16, D_ / 128, E_), dim3(256), 0, stream,
                       act, offs, 0, dk, D_, F_, eo);
    hipLaunchKernelGGL(gemm2_old, dim3(16, D_ / 128, 1), dim3(256), 0, stream,
                       act_sh, (const int*)nullptr, N_, sd, D_, FS_, sh_out);
    hipLaunchKernelGGL(combine_k, dim3((N_ * D_ / 4) / 256), dim3(256), 0, stream,
                       eo, sh_out, topw, slot_of, out);
  }
}